// Round 7
// baseline (54.291 us; speedup 1.0000x reference)
//
#include <hip/hip_runtime.h>

// FCOS Revision_PRED refinement.
// Outputs (flat float32, in return order):
//   [0, N2*4)              refined_boxes [N2,4]
//   [N2*4, N2*5)           s2            [N2]
//   [N2*5, N2*6)           c2            [N2] (int -> float)
//   [N2*6, N2*6+N1)        missing_mask  [N1] (bool -> 0/1)
//   [N2*6+N1, ...)         ious          [N1,N2]
//
// Algebraic reductions vs the reference:
//  - columns are independent under the iterative suppression; the <=8
//    suppressed entries + final winner are exactly the column's entries
//    >0.5 in (value desc, row asc) order -> per-column top-9 suffices.
//  - entries >0.5 are rare: extract via atomic append (e-major layout so
//    the merge kernel reads them coalesced), not dense per-split lists.
//  - missing_mask is invariant under suppression (>0.5 -> ==0.5 both fail
//    iou<0.5): row flags come from the v>=0.5 hits directly.
// Numerics:
//  - bulk path: v_rcp + 1 Newton (<=2ulp). Any value > 0.499999 is
//    recomputed with __fdiv_rn, so everything near/above the 0.5
//    threshold -- i.e. everything that participates in selection -- is
//    bit-exact vs numpy. un is built with __f*_rn (no FMA contraction).
// Memory:
//  - ious stores are NONTEMPORAL (native ext_vector_type float4 -- HIP's
//    float4 class is rejected by the builtin): the 134 MB matrix is
//    written once and (by us) never re-read except the rare cross-kernel
//    overflow rescan. Round-5 inference: A ran at ~3.4 TB/s (vs 6.6 TB/s
//    fill-path) while being VALU-sensitive -- consistent with L2
//    write-allocate doubling HBM traffic. nt stores bypass L2 allocation.

typedef float vfloat4 __attribute__((ext_vector_type(4)));

constexpr int TOPK = 9;  // up to 8 suppressions + final winner

__device__ __forceinline__ void key_insert(unsigned long long (&t)[TOPK],
                                           unsigned long long pk) {
    if (pk > t[TOPK - 1]) {
#pragma unroll
        for (int j = TOPK - 1; j >= 0; --j) {
            const bool gt_cur  = pk > t[j];
            const bool gt_prev = (j > 0) ? (pk > t[j - 1]) : false;
            if (gt_cur) t[j] = gt_prev ? t[j - 1] : pk;
        }
    }
}

// ---------------------------------------------------------------------------
// Kernel A: IoU matrix (4 cols/thread, nontemporal float4 stores) + rare
// candidate append (e-major) + row flags. blockIdx.y = row split.
// n2 assumed multiple of 4 (4096 here).
// ---------------------------------------------------------------------------
__global__ __launch_bounds__(256) void iou_cand_kernel(
    const float* __restrict__ b1, const float* __restrict__ b2,
    float* __restrict__ ious,
    unsigned int* __restrict__ cnt, unsigned long long* __restrict__ cand,
    unsigned char* __restrict__ rowflag,
    int n1, int n2, int rps, int cap)
{
    const int tid = blockIdx.x * blockDim.x + threadIdx.x;
    const int c0 = tid * 4;
    if (c0 >= n2) return;
    const int r0 = blockIdx.y * rps;
    const int r1 = min(r0 + rps, n1);

    float4 bx[4]; float ar[4];
#pragma unroll
    for (int k = 0; k < 4; ++k) {
        bx[k] = reinterpret_cast<const float4*>(b2)[c0 + k];
        ar[k] = __fmul_rn(__fsub_rn(bx[k].z, bx[k].x),
                          __fsub_rn(bx[k].w, bx[k].y));
    }

    float* orow = ious + (size_t)r0 * n2 + c0;
    for (int r = r0; r < r1; ++r, orow += n2) {
        const float4 p = reinterpret_cast<const float4*>(b1)[r];  // wave-uniform
        const float a1 = __fmul_rn(__fsub_rn(p.z, p.x), __fsub_rn(p.w, p.y));
        float v[4], ovs[4], uns[4];
#pragma unroll
        for (int k = 0; k < 4; ++k) {
            const float wx = fmaxf(__fsub_rn(fminf(p.z, bx[k].z),
                                             fmaxf(p.x, bx[k].x)), 0.0f);
            const float wy = fmaxf(__fsub_rn(fminf(p.w, bx[k].w),
                                             fmaxf(p.y, bx[k].y)), 0.0f);
            const float ov = __fmul_rn(wx, wy);
            const float un = fmaxf(__fsub_rn(__fadd_rn(a1, ar[k]), ov), 1e-6f);
            ovs[k] = ov; uns[k] = un;
            float rc = __builtin_amdgcn_rcpf(un);
            rc = rc * fmaf(-un, rc, 2.0f);        // 1 Newton step, <=2 ulp
            v[k] = ov * rc;
        }

        // near-threshold lanes: make bit-exact, flag rows, append candidates.
        // 0.499999 is ~17 ulps below 0.5 -- covers the <=2ulp NR error band.
        const float vmax = fmaxf(fmaxf(v[0], v[1]), fmaxf(v[2], v[3]));
        if (vmax > 0.499999f) {                    // rare wave branch
#pragma unroll
            for (int k = 0; k < 4; ++k) {
                if (v[k] > 0.499999f) {
                    const float ve = __fdiv_rn(ovs[k], uns[k]);  // exact vs np
                    v[k] = ve;
                    if (ve >= 0.5f) {
                        rowflag[r] = 1;
                        if (ve > 0.5f) {
                            const unsigned int idx = atomicAdd(&cnt[c0 + k], 1u);
                            if (idx < (unsigned int)cap)
                                // key packs (value desc, row asc): ties ->
                                // smaller r (larger ~r) wins, as jnp.argmax.
                                cand[(size_t)idx * n2 + (c0 + k)] =
                                    ((unsigned long long)__float_as_uint(ve) << 32)
                                  | (unsigned long long)(~(unsigned int)r);
                        }
                    }
                }
            }
        }
        vfloat4 vo; vo.x = v[0]; vo.y = v[1]; vo.z = v[2]; vo.w = v[3];
        __builtin_nontemporal_store(vo, reinterpret_cast<vfloat4*>(orow));
    }
}

// ---------------------------------------------------------------------------
// Kernel B (fused refine + missing): per column, top-9 from the candidate
// list (u64 keys -> append-order independent), simulate <=8 suppressions,
// scatter the 0.5s, write boxes/scores/classes; threads >= n2 handle rows'
// missing_mask. Overflowed columns (cnt > cap) rescan their ious column.
// ---------------------------------------------------------------------------
__global__ __launch_bounds__(64) void refine_missing_kernel(
    const float* __restrict__ b1, const float* __restrict__ s1,
    const int* __restrict__ c1,
    const float* __restrict__ b2, const float* __restrict__ s2,
    const int* __restrict__ c2,
    const unsigned int* __restrict__ cnt,
    const unsigned long long* __restrict__ cand,
    const unsigned char* __restrict__ rowflag,
    float* __restrict__ out_boxes, float* __restrict__ out_s,
    float* __restrict__ out_c, float* __restrict__ out_m,
    float* __restrict__ ious,
    int n1, int n2, int cap)
{
    const int tid = blockIdx.x * blockDim.x + threadIdx.x;

    if (tid < n1)                                   // missing_mask part
        out_m[tid] = rowflag[tid] ? 0.0f : 1.0f;

    const int c = tid;
    if (c >= n2) return;

    unsigned long long t[TOPK];
#pragma unroll
    for (int j = 0; j < TOPK; ++j) t[j] = 0ull;     // 0 < any valid key

    const int n = (int)cnt[c];
    if (n <= cap) {
        const unsigned long long* L = cand + c;     // e-major: coalesced
        for (int e = 0; e < n; ++e)
            key_insert(t, L[(size_t)e * n2]);
    } else {                                        // overflow: rescan column
        for (int r = 0; r < n1; ++r) {
            const float v = ious[(size_t)r * n2 + c];
            if (v > 0.5f)
                key_insert(t, ((unsigned long long)__float_as_uint(v) << 32)
                            | (unsigned long long)(~(unsigned int)r));
        }
    }

    int m = 0;
#pragma unroll
    for (int j = 0; j < TOPK; ++j) m += (t[j] != 0ull) ? 1 : 0;

    int   ti[TOPK];
    float s1v[TOPK];
    const float s2c = s2[c];
#pragma unroll
    for (int j = 0; j < TOPK; ++j) {
        ti[j]  = (int)~(unsigned int)(t[j] & 0xffffffffull);
        s1v[j] = (j < m) ? s1[ti[j]] : 0.0f;
    }

    // k = length of maximal prefix with scores1 < scores2 (suppressed), cap 8
    int k = 0;
#pragma unroll
    for (int j = 0; j < 8; ++j)
        if (j < m && k == j && s1v[j] < s2c) k = j + 1;

    // scatter the suppressions (entries replaced by exactly 0.5)
#pragma unroll
    for (int j = 0; j < 8; ++j)
        if (j < k) ious[(size_t)ti[j] * n2 + c] = 0.5f;

    const bool refine = (k < m);
    int winner = 0; float wsc = 0.0f;
#pragma unroll
    for (int j = 0; j < TOPK; ++j)
        if (j == k) { winner = ti[j]; wsc = s1v[j]; }

    float4 ob; float os, oc;
    if (refine) {
        ob = reinterpret_cast<const float4*>(b1)[winner];
        os = wsc;
        oc = (float)c1[winner];
    } else {
        ob = reinterpret_cast<const float4*>(b2)[c];
        os = s2c;
        oc = (float)c2[c];
    }
    ob.x = fmaxf(ob.x, 0.0f); ob.y = fmaxf(ob.y, 0.0f);   // (b+|b|)*0.5
    ob.z = fmaxf(ob.z, 0.0f); ob.w = fmaxf(ob.w, 0.0f);
    reinterpret_cast<float4*>(out_boxes)[c] = ob;
    out_s[c] = os;
    out_c[c] = oc;
}

extern "C" void kernel_launch(void* const* d_in, const int* in_sizes, int n_in,
                              void* d_out, int out_size, void* d_ws, size_t ws_size,
                              hipStream_t stream) {
    (void)n_in; (void)out_size;
    const float* b1 = (const float*)d_in[0];
    const float* s1 = (const float*)d_in[1];
    const int*   c1 = (const int*)d_in[2];
    const float* b2 = (const float*)d_in[3];
    const float* s2 = (const float*)d_in[4];
    const int*   c2 = (const int*)d_in[5];
    const int n1 = in_sizes[1];   // 8192
    const int n2 = in_sizes[4];   // 4096

    float* out       = (float*)d_out;
    float* out_boxes = out;
    float* out_s     = out + (size_t)n2 * 4;
    float* out_c     = out_s + n2;
    float* out_m     = out_c + n2;
    float* out_ious  = out_m + n1;

    // ws: [cnt: n2 u32][rowflag: n1 u8][cand: cap*n2 u64, e-major]
    const size_t cnt_b    = (size_t)n2 * sizeof(unsigned int);
    const size_t flag_b   = (size_t)n1;
    const size_t cand_off = (cnt_b + flag_b + 15) & ~(size_t)15;
    int cap = 1024;                                // overflow path covers rest
    while (cap > 16 && cand_off + (size_t)cap * n2 * 8 > ws_size) cap >>= 1;
    unsigned int*       cnt     = (unsigned int*)d_ws;
    unsigned char*      rowflag = (unsigned char*)d_ws + cnt_b;
    unsigned long long* cand    = (unsigned long long*)((char*)d_ws + cand_off);

    (void)hipMemsetAsync(d_ws, 0, cnt_b + flag_b, stream);

    const int bx = (n2 / 4 + 255) / 256;           // 4 at n2=4096
    int S = 2048 / bx; if (S < 1) S = 1; if (S > n1) S = n1;   // 512 splits
    const int rps = (n1 + S - 1) / S;              // 16 rows/block

    dim3 gridA(bx, S);
    iou_cand_kernel<<<gridA, 256, 0, stream>>>(b1, b2, out_ious, cnt, cand,
                                               rowflag, n1, n2, rps, cap);
    const int ntot = max(n1, n2);
    refine_missing_kernel<<<(ntot + 63) / 64, 64, 0, stream>>>(
        b1, s1, c1, b2, s2, c2, cnt, cand, rowflag,
        out_boxes, out_s, out_c, out_m, out_ious, n1, n2, cap);
}